// Round 1
// baseline (775.422 us; speedup 1.0000x reference)
//
#include <hip/hip_runtime.h>
#include <math.h>

#define NN 128
#define CC 64
#define TT 288
#define VV 16
#define SS 3
#define ICC 16
#define TC 8    // k_logits time chunk
#define TLT 8   // k_out time tile

// ---------------------------------------------------------------------------
// K0: WdT[s][c][o] = Wd[s][o][c]  (12288 elements)
// ---------------------------------------------------------------------------
__global__ void k_wdt(const float* __restrict__ Wd, float* __restrict__ WdT) {
    int e = blockIdx.x * 256 + threadIdx.x;
    if (e < SS * CC * CC) {
        int s = e / (CC * CC);
        int r = e % (CC * CC);
        int o = r / CC;
        int c = r % CC;
        WdT[(s * CC + c) * CC + o] = Wd[e];
    }
}

// ---------------------------------------------------------------------------
// K1: att logits[n,s,v,w] = (1/(IC*T)) * sum_{i,t} fa[i,t,v]*fb[i,t,w]
//     fa[i,t,v] = sum_c Wa[s,i,c] x[n,c,t,v] + ba[s,i]   (fb analogous)
// One block per (n,s). 256 threads. T in chunks of TC=8.
// ---------------------------------------------------------------------------
__global__ __launch_bounds__(256) void k_logits(
    const float* __restrict__ x,
    const float* __restrict__ Wa, const float* __restrict__ ba,
    const float* __restrict__ Wb, const float* __restrict__ bb,
    float* __restrict__ logits)
{
    const int n = blockIdx.x / SS;
    const int s = blockIdx.x % SS;

    __shared__ __align__(16) float xs[CC * TC * VV];   // [c][tt*16+v], 8192 floats
    __shared__ __align__(16) float fab[32 * TC * VV];  // rows 0..15 fa(i), 16..31 fb(i)
    __shared__ __align__(16) float Wabs[32 * CC];      // rows 0..15 Wa, 16..31 Wb
    __shared__ float babs[32];

    const int tid = threadIdx.x;

    for (int e = tid; e < ICC * CC; e += 256) {
        Wabs[e]            = Wa[s * ICC * CC + e];
        Wabs[ICC * CC + e] = Wb[s * ICC * CC + e];
    }
    if (tid < ICC) {
        babs[tid]      = ba[s * ICC + tid];
        babs[16 + tid] = bb[s * ICC + tid];
    }

    const int v  = tid >> 4;          // 0..15
    const int w  = tid & 15;          // 0..15
    const int r0 = (tid >> 5) * 4;    // row base 0..28 (covers 32 rows)
    const int j0 = (tid & 31) * 4;    // col base 0..124 (covers 128 cols)

    float acc = 0.f;
    const float* xn = x + (size_t)n * CC * TT * VV;

    for (int t0 = 0; t0 < TT; t0 += TC) {
        __syncthreads();
        // stage x chunk: xs[c][tt*16+v] -- 128 contiguous floats per c
        for (int e = tid; e < CC * TC * VV; e += 256) {
            int c = e >> 7;
            int r = e & 127;
            xs[e] = xn[(size_t)c * TT * VV + t0 * VV + r];
        }
        __syncthreads();

        // fa/fb 4x4 register-tiled GEMM: rows r0..r0+3, cols j0..j0+3, K=64
        {
            float accf[4][4];
#pragma unroll
            for (int i = 0; i < 4; ++i) {
                float b = babs[r0 + i];
                accf[i][0] = b; accf[i][1] = b; accf[i][2] = b; accf[i][3] = b;
            }
            for (int c = 0; c < CC; ++c) {
                float4 xv = *(const float4*)&xs[c * 128 + j0];
#pragma unroll
                for (int i = 0; i < 4; ++i) {
                    float wv = Wabs[(r0 + i) * CC + c];
                    accf[i][0] += wv * xv.x;
                    accf[i][1] += wv * xv.y;
                    accf[i][2] += wv * xv.z;
                    accf[i][3] += wv * xv.w;
                }
            }
#pragma unroll
            for (int i = 0; i < 4; ++i) {
                *(float4*)&fab[(r0 + i) * 128 + j0] =
                    make_float4(accf[i][0], accf[i][1], accf[i][2], accf[i][3]);
            }
        }
        __syncthreads();

        // att accumulation: thread (v,w)
#pragma unroll 8
        for (int it = 0; it < ICC * TC; ++it) {
            int i  = it >> 3;
            int tt = it & 7;
            acc += fab[i * 128 + tt * 16 + v] * fab[(16 + i) * 128 + tt * 16 + w];
        }
    }

    logits[(((size_t)n * SS + s) * VV + v) * VV + w] = acc * (1.0f / (ICC * TT));
}

// ---------------------------------------------------------------------------
// K2: softmax over v (axis=2) per (n,s,w), then + (A_base+PA)[s,v,w]
// ---------------------------------------------------------------------------
__global__ __launch_bounds__(256) void k_softmax(
    const float* __restrict__ logits,
    const float* __restrict__ A_base, const float* __restrict__ PA,
    float* __restrict__ att)
{
    const int n = blockIdx.x / SS;
    const int s = blockIdx.x % SS;
    const int tid = threadIdx.x;       // = v*16 + w
    const int w = tid & 15;

    __shared__ float l[256];
    size_t base = ((size_t)n * SS + s) * 256;
    float mine = logits[base + tid];
    l[tid] = mine;
    __syncthreads();

    float mx = -1e30f;
#pragma unroll
    for (int v2 = 0; v2 < 16; ++v2) mx = fmaxf(mx, l[v2 * 16 + w]);
    float sm = 0.f;
#pragma unroll
    for (int v2 = 0; v2 < 16; ++v2) sm += __expf(l[v2 * 16 + w] - mx);
    float r = __expf(mine - mx) / sm;

    int aidx = (s * VV * VV) + tid;    // (s,v,w)
    att[base + tid] = r + A_base[aidx] + PA[aidx];
}

// ---------------------------------------------------------------------------
// K3: out[n,o,t,w] = (sum_{s,c} Wd[s,o,c] * sum_v x[n,c,t,v] att[n,s,v,w]
//                    + bd.sum(0)[o]) * scale[o] + beta[o] + x[n,o,t,w]
// One block per (n, t-tile of 8). 256 threads.
// ---------------------------------------------------------------------------
__global__ __launch_bounds__(256) void k_out(
    const float* __restrict__ x, const float* __restrict__ att,
    const float* __restrict__ WdT,     // [S][C][C], o contiguous
    const float* __restrict__ bd,
    const float* __restrict__ gamma, const float* __restrict__ beta,
    float* __restrict__ out)
{
    const int n  = blockIdx.x / (TT / TLT);
    const int tb = blockIdx.x % (TT / TLT);
    const int t0 = tb * TLT;
    const int tid = threadIdx.x;

    __shared__ __align__(16) float xs[CC * TLT * VV];   // [c][tw], 8192
    __shared__ __align__(16) float zs[CC * TLT * VV];   // [c][tw], 8192
    __shared__ __align__(16) float atts[SS * VV * VV];  // 768

    const float* xn = x + (size_t)n * CC * TT * VV;
    for (int e = tid; e < CC * TLT * VV; e += 256) {
        int c = e >> 7;
        int r = e & 127;
        xs[e] = xn[(size_t)c * TT * VV + t0 * VV + r];
    }
    for (int e = tid; e < SS * VV * VV; e += 256)
        atts[e] = att[(size_t)n * SS * VV * VV + e];

    // y mapping: 8 o-rows x 4 tw-cols per thread
    const int o0 = (tid >> 5) * 8;
    const int j0 = (tid & 31) * 4;
    float acc[8][4] = {};

    // z mapping: thread owns one tw column, 32 c-rows
    const int tw  = tid & 127;
    const int c0  = (tid >> 7) * 32;
    const int wz  = tw & 15;
    const int ttz = tw >> 4;

    for (int s = 0; s < SS; ++s) {
        __syncthreads();   // s=0: staging done; s>0: previous y-accum done reading zs
        // z[c][tw] = sum_v xs[c][ttz*16+v] * att[s][v][wz]
        float av[16];
#pragma unroll
        for (int v2 = 0; v2 < 16; ++v2) av[v2] = atts[(s * VV + v2) * VV + wz];
        for (int c = c0; c < c0 + 32; ++c) {
            const float4* xp = (const float4*)&xs[c * 128 + ttz * 16];
            float4 x0 = xp[0], x1 = xp[1], x2 = xp[2], x3 = xp[3];
            float z = x0.x * av[0]  + x0.y * av[1]  + x0.z * av[2]  + x0.w * av[3]
                    + x1.x * av[4]  + x1.y * av[5]  + x1.z * av[6]  + x1.w * av[7]
                    + x2.x * av[8]  + x2.y * av[9]  + x2.z * av[10] + x2.w * av[11]
                    + x3.x * av[12] + x3.y * av[13] + x3.z * av[14] + x3.w * av[15];
            zs[c * 128 + tw] = z;
        }
        __syncthreads();
        // y += Wd_s @ z  (64x128, K=64)
        const float* wdt = WdT + (size_t)s * CC * CC;
#pragma unroll 4
        for (int c = 0; c < CC; ++c) {
            float4 zv = *(const float4*)&zs[c * 128 + j0];
            float4 w0 = *(const float4*)&wdt[c * CC + o0];
            float4 w1 = *(const float4*)&wdt[c * CC + o0 + 4];
            float wv[8] = {w0.x, w0.y, w0.z, w0.w, w1.x, w1.y, w1.z, w1.w};
#pragma unroll
            for (int i = 0; i < 8; ++i) {
                acc[i][0] += wv[i] * zv.x;
                acc[i][1] += wv[i] * zv.y;
                acc[i][2] += wv[i] * zv.z;
                acc[i][3] += wv[i] * zv.w;
            }
        }
    }

    // epilogue: bias, BN (inference), beta, residual
    const float bninv = 1.0f / sqrtf(1.0f + 1e-5f);
#pragma unroll
    for (int i = 0; i < 8; ++i) {
        int o = o0 + i;
        float bds = bd[o] + bd[CC + o] + bd[2 * CC + o];
        float sc  = gamma[o] * bninv;
        float be  = beta[o];
        float4 xv = *(const float4*)&xs[o * 128 + j0];
        float4 r;
        r.x = (acc[i][0] + bds) * sc + be + xv.x;
        r.y = (acc[i][1] + bds) * sc + be + xv.y;
        r.z = (acc[i][2] + bds) * sc + be + xv.z;
        r.w = (acc[i][3] + bds) * sc + be + xv.w;
        *(float4*)&out[(size_t)(n * CC + o) * TT * VV + t0 * VV + j0] = r;
    }
}

// ---------------------------------------------------------------------------
extern "C" void kernel_launch(void* const* d_in, const int* in_sizes, int n_in,
                              void* d_out, int out_size, void* d_ws, size_t ws_size,
                              hipStream_t stream) {
    const float* x      = (const float*)d_in[0];
    const float* A_base = (const float*)d_in[1];
    const float* PA     = (const float*)d_in[2];
    const float* Wa     = (const float*)d_in[3];
    const float* ba     = (const float*)d_in[4];
    const float* Wb     = (const float*)d_in[5];
    const float* bb     = (const float*)d_in[6];
    const float* Wd     = (const float*)d_in[7];
    const float* bd     = (const float*)d_in[8];
    const float* gamma  = (const float*)d_in[9];
    const float* beta   = (const float*)d_in[10];
    float* out = (float*)d_out;

    float* logits = (float*)d_ws;                        // [N,S,V,V]
    float* att    = logits + (size_t)NN * SS * VV * VV;  // [N,S,V,V]
    float* WdT    = att    + (size_t)NN * SS * VV * VV;  // [S,C,C]

    k_wdt<<<(SS * CC * CC + 255) / 256, 256, 0, stream>>>(Wd, WdT);
    k_logits<<<NN * SS, 256, 0, stream>>>(x, Wa, ba, Wb, bb, logits);
    k_softmax<<<NN * SS, 256, 0, stream>>>(logits, A_base, PA, att);
    k_out<<<NN * (TT / TLT), 256, 0, stream>>>(x, att, WdT, bd, gamma, beta, out);
}

// Round 2
// 624.398 us; speedup vs baseline: 1.2419x; 1.2419x over previous
//
#include <hip/hip_runtime.h>
#include <math.h>

#define NN 128
#define CC 64
#define TT 288
#define VV 16
#define SS 3
#define ICC 16

typedef __attribute__((ext_vector_type(8))) short s16x8;
typedef __attribute__((ext_vector_type(4))) float f32x4;

#define MFMA16(a, b, c) __builtin_amdgcn_mfma_f32_16x16x32_bf16(a, b, c, 0, 0, 0)

__device__ __forceinline__ unsigned short f2bf(float f) {
    union { float f; unsigned u; } x; x.f = f;
    unsigned r = (x.u + 0x7FFFu + ((x.u >> 16) & 1u)) >> 16;
    return (unsigned short)r;
}

__device__ __forceinline__ s16x8 zero8() {
    s16x8 z;
#pragma unroll
    for (int j = 0; j < 8; ++j) z[j] = 0;
    return z;
}

// 8 floats from 16B-aligned global/LDS pointer -> bf16 frag
__device__ __forceinline__ s16x8 cvt8g(const float* p) {
    float4 a = *(const float4*)p;
    float4 b = *(const float4*)(p + 4);
    s16x8 r;
    r[0] = (short)f2bf(a.x); r[1] = (short)f2bf(a.y);
    r[2] = (short)f2bf(a.z); r[3] = (short)f2bf(a.w);
    r[4] = (short)f2bf(b.x); r[5] = (short)f2bf(b.y);
    r[6] = (short)f2bf(b.z); r[7] = (short)f2bf(b.w);
    return r;
}

// 8 floats from possibly 4B-aligned LDS pointer (odd-pad rows) -> bf16 frag
__device__ __forceinline__ s16x8 cvt8u(const float* p) {
    s16x8 r;
#pragma unroll
    for (int j = 0; j < 8; ++j) r[j] = (short)f2bf(p[j]);
    return r;
}

// ---------------------------------------------------------------------------
// K0: epilogue coefficients. mul[o] = gamma*rsqrt(1+eps);
//     add[o] = (sum_s bd[s][o])*mul[o] + beta[o]
// ---------------------------------------------------------------------------
__global__ void k_prep(const float* __restrict__ bd, const float* __restrict__ gamma,
                       const float* __restrict__ beta,
                       float* __restrict__ cmul, float* __restrict__ cadd) {
    int o = threadIdx.x;
    if (o < CC) {
        float mul = gamma[o] * rsqrtf(1.0f + 1e-5f);
        float add = (bd[o] + bd[CC + o] + bd[2 * CC + o]) * mul + beta[o];
        cmul[o] = mul;
        cadd[o] = add;
    }
}

// ---------------------------------------------------------------------------
// K1: logits partials via MFMA.
// Block = (n, s, half). Chunk of 8 t's: stage x fp32 [col][c] pad65 in LDS;
// fa/fb = Wa/Wb @ x (MFMA, bias in acc init); fa/fb bf16 -> LDS [v][k=(t,i)];
// logits += fa^T fb (MFMA over k). Per-wave k-slices; cross-wave reduce at end.
// ---------------------------------------------------------------------------
__global__ __launch_bounds__(256) void k_logits(
    const float* __restrict__ x,
    const float* __restrict__ Wa, const float* __restrict__ ba,
    const float* __restrict__ Wb, const float* __restrict__ bb,
    float* __restrict__ part)   // [2][N][S][256]
{
    const int b = blockIdx.x;
    const int n = b / (SS * 2);
    const int rem = b % (SS * 2);
    const int s = rem >> 1;
    const int half = rem & 1;

    const int tid  = threadIdx.x;
    const int lane = tid & 63;
    const int wave = tid >> 6;
    const int q    = lane >> 4;
    const int m    = lane & 15;

    __shared__ __align__(16) float xs[128 * 65];            // [col][c] pad 65
    __shared__ __align__(16) unsigned short fa_l[16 * 136]; // [v][k] k=t*16+i
    __shared__ __align__(16) unsigned short fb_l[16 * 136]; // [w][k]

    // A-frags for Wa/Wb: A[i=m][k = kt*32 + q*8 + j]
    s16x8 wa[2], wb[2];
#pragma unroll
    for (int kt = 0; kt < 2; ++kt) {
        wa[kt] = cvt8g(Wa + ((size_t)(s * ICC + m) * CC + kt * 32 + q * 8));
        wb[kt] = cvt8g(Wb + ((size_t)(s * ICC + m) * CC + kt * 32 + q * 8));
    }
    const float4 bias_a = *(const float4*)(ba + s * ICC + q * 4);
    const float4 bias_b = *(const float4*)(bb + s * ICC + q * 4);

    f32x4 accL;
#pragma unroll
    for (int r = 0; r < 4; ++r) accL[r] = 0.0f;

    const float* xn = x + (size_t)n * CC * TT * VV;

    for (int ch = 0; ch < 18; ++ch) {
        const int t00 = (half * 18 + ch) * 8;
        __syncthreads();
        // stage: xs[col][c] = x[c][t00*16 + col], col = tl*16+v
#pragma unroll
        for (int it = 0; it < 32; ++it) {
            int e = tid + it * 256;
            int c = e >> 7, col = e & 127;
            xs[col * 65 + c] = xn[(size_t)c * TT * VV + t00 * VV + col];
        }
        __syncthreads();

        // stage 1: wave handles t-locals {2*wave, 2*wave+1}
#pragma unroll
        for (int tli = 0; tli < 2; ++tli) {
            const int tl = wave * 2 + tli;
            s16x8 bx[2];
#pragma unroll
            for (int kt = 0; kt < 2; ++kt)
                bx[kt] = cvt8u(&xs[(tl * 16 + m) * 65 + kt * 32 + q * 8]);
            f32x4 aa, ab;
            aa[0] = bias_a.x; aa[1] = bias_a.y; aa[2] = bias_a.z; aa[3] = bias_a.w;
            ab[0] = bias_b.x; ab[1] = bias_b.y; ab[2] = bias_b.z; ab[3] = bias_b.w;
#pragma unroll
            for (int kt = 0; kt < 2; ++kt) {
                aa = MFMA16(wa[kt], bx[kt], aa);
                ab = MFMA16(wb[kt], bx[kt], ab);
            }
            // D[i = 4q+r][v = m] -> fa_l[v][k = tl*16 + i]
#pragma unroll
            for (int r = 0; r < 4; ++r) {
                fa_l[m * 136 + tl * 16 + 4 * q + r] = f2bf(aa[r]);
                fb_l[m * 136 + tl * 16 + 4 * q + r] = f2bf(ab[r]);
            }
        }
        // stage 2: this wave's k-slice k0 = wave*32 (exactly the t's it wrote)
        s16x8 A2 = *(const s16x8*)&fa_l[m * 136 + wave * 32 + q * 8];
        s16x8 B2 = *(const s16x8*)&fb_l[m * 136 + wave * 32 + q * 8];
        accL = MFMA16(A2, B2, accL);
    }

    // cross-wave reduction (reuse xs)
    __syncthreads();
    float* red = xs;
#pragma unroll
    for (int r = 0; r < 4; ++r)
        red[wave * 256 + (4 * q + r) * 16 + m] = accL[r];
    __syncthreads();
    if (tid < 256) {
        float v = red[tid] + red[256 + tid] + red[512 + tid] + red[768 + tid];
        part[((size_t)(half * NN + n) * SS + s) * 256 + tid] = v;
    }
}

// ---------------------------------------------------------------------------
// K2: sum partials, scale, softmax over v, add A_base+PA
// ---------------------------------------------------------------------------
__global__ __launch_bounds__(256) void k_softmax(
    const float* __restrict__ p0, const float* __restrict__ p1,
    const float* __restrict__ A_base, const float* __restrict__ PA,
    float* __restrict__ att)
{
    const int n = blockIdx.x / SS;
    const int s = blockIdx.x % SS;
    const int tid = threadIdx.x;       // = v*16 + w
    const int w = tid & 15;

    __shared__ float l[256];
    size_t base = ((size_t)n * SS + s) * 256;
    float mine = (p0[base + tid] + p1[base + tid]) * (1.0f / (ICC * TT));
    l[tid] = mine;
    __syncthreads();

    float mx = -1e30f;
#pragma unroll
    for (int v2 = 0; v2 < 16; ++v2) mx = fmaxf(mx, l[v2 * 16 + w]);
    float sm = 0.f;
#pragma unroll
    for (int v2 = 0; v2 < 16; ++v2) sm += __expf(l[v2 * 16 + w] - mx);
    float r = __expf(mine - mx) / sm;

    int aidx = (s * VV * VV) + tid;
    att[base + tid] = r + A_base[aidx] + PA[aidx];
}

// ---------------------------------------------------------------------------
// K3: out = (sum_s Wd_s @ (x (.) att_s)) * cmul + cadd + x, all via MFMA.
// Block = (n, 8-t tile); each wave privately owns 2 t's (32 cols).
// Z stage: K=16 (v) zero-padded to 32. Y stage: K=64 (c). acc across s.
// ---------------------------------------------------------------------------
__global__ __launch_bounds__(256) void k_out(
    const float* __restrict__ x, const float* __restrict__ att,
    const float* __restrict__ Wd,
    const float* __restrict__ cmul, const float* __restrict__ cadd,
    float* __restrict__ out)
{
    const int b  = blockIdx.x;
    const int n  = b / (TT / 8);
    const int t0 = (b % (TT / 8)) * 8;

    const int tid  = threadIdx.x;
    const int lane = tid & 63;
    const int wave = tid >> 6;
    const int q    = lane >> 4;
    const int m    = lane & 15;

    __shared__ __align__(16) float zs[4 * 32 * 65];          // per-wave [col][c] pad65
    __shared__ __align__(16) unsigned short attL[SS * 16 * 24]; // [s][w][v] pad24

    for (int e = tid; e < SS * 256; e += 256) {
        int ss = e >> 8, vv = (e >> 4) & 15, ww = e & 15;
        attL[(ss * 16 + ww) * 24 + vv] =
            f2bf(att[((size_t)n * SS + ss) * 256 + vv * 16 + ww]);
    }

    // x A-frags: A[c_local = m][k = v], lanes q>=2 zero (K padded 16->32)
    s16x8 xf[4][2];
#pragma unroll
    for (int cc = 0; cc < 4; ++cc)
#pragma unroll
        for (int u = 0; u < 2; ++u) {
            s16x8 f = zero8();
            if (q < 2) {
                const float* p = x + ((size_t)(n * CC + cc * 16 + m) * TT +
                                      (t0 + wave * 2 + u)) * VV + q * 8;
                f = cvt8g(p);
            }
            xf[cc][u] = f;
        }

    __syncthreads();

    f32x4 acc[4][2];
#pragma unroll
    for (int p = 0; p < 4; ++p)
#pragma unroll
        for (int u = 0; u < 2; ++u)
#pragma unroll
            for (int r = 0; r < 4; ++r) acc[p][u][r] = 0.0f;

    float* zw = zs + wave * (32 * 65);

    for (int s = 0; s < SS; ++s) {
        // B-frag of att: B[k=v][n=w], zero for k>=16
        s16x8 af = zero8();
        if (q < 2) af = *(const s16x8*)&attL[(s * 16 + m) * 24 + q * 8];

        // Z = x . att  -> zs fp32 [col = u*16 + w][c]
#pragma unroll
        for (int u = 0; u < 2; ++u)
#pragma unroll
            for (int cc = 0; cc < 4; ++cc) {
                f32x4 z;
#pragma unroll
                for (int r = 0; r < 4; ++r) z[r] = 0.0f;
                z = MFMA16(xf[cc][u], af, z);
#pragma unroll
                for (int r = 0; r < 4; ++r)
                    zw[(u * 16 + m) * 65 + cc * 16 + 4 * q + r] = z[r];
            }

        // B-frags of Z: B[k=c][n=col]
        s16x8 zf[2][2];
#pragma unroll
        for (int u = 0; u < 2; ++u)
#pragma unroll
            for (int kt = 0; kt < 2; ++kt)
                zf[u][kt] = cvt8u(&zw[(u * 16 + m) * 65 + kt * 32 + q * 8]);

        // Y += Wd_s @ Z
#pragma unroll
        for (int p = 0; p < 4; ++p) {
            s16x8 wf[2];
#pragma unroll
            for (int kt = 0; kt < 2; ++kt)
                wf[kt] = cvt8g(Wd + ((size_t)(s * CC + p * 16 + m) * CC +
                                     kt * 32 + q * 8));
#pragma unroll
            for (int u = 0; u < 2; ++u)
#pragma unroll
                for (int kt = 0; kt < 2; ++kt)
                    acc[p][u] = MFMA16(wf[kt], zf[u][kt], acc[p][u]);
        }
    }

    // epilogue: D[o = p*16+4q+r][col = u*16+m -> (t,w)]
#pragma unroll
    for (int p = 0; p < 4; ++p) {
        float4 mu = *(const float4*)(cmul + p * 16 + 4 * q);
        float4 ad = *(const float4*)(cadd + p * 16 + 4 * q);
        float mur[4] = {mu.x, mu.y, mu.z, mu.w};
        float adr[4] = {ad.x, ad.y, ad.z, ad.w};
#pragma unroll
        for (int u = 0; u < 2; ++u) {
            int t = t0 + wave * 2 + u;
#pragma unroll
            for (int r = 0; r < 4; ++r) {
                int o = p * 16 + 4 * q + r;
                size_t gi = ((size_t)(n * CC + o) * TT + t) * VV + m;
                out[gi] = acc[p][u][r] * mur[r] + adr[r] + x[gi];
            }
        }
    }
}

// ---------------------------------------------------------------------------
extern "C" void kernel_launch(void* const* d_in, const int* in_sizes, int n_in,
                              void* d_out, int out_size, void* d_ws, size_t ws_size,
                              hipStream_t stream) {
    const float* x      = (const float*)d_in[0];
    const float* A_base = (const float*)d_in[1];
    const float* PA     = (const float*)d_in[2];
    const float* Wa     = (const float*)d_in[3];
    const float* ba     = (const float*)d_in[4];
    const float* Wb     = (const float*)d_in[5];
    const float* bb     = (const float*)d_in[6];
    const float* Wd     = (const float*)d_in[7];
    const float* bd     = (const float*)d_in[8];
    const float* gamma  = (const float*)d_in[9];
    const float* beta   = (const float*)d_in[10];
    float* out = (float*)d_out;

    float* part = (float*)d_ws;                        // [2][N][S][256]
    float* p0   = part;
    float* p1   = part + (size_t)NN * SS * 256;
    float* att  = part;                                // overlays p0 (safe)
    float* cmul = part + (size_t)2 * NN * SS * 256;
    float* cadd = cmul + CC;

    k_prep<<<1, 64, 0, stream>>>(bd, gamma, beta, cmul, cadd);
    k_logits<<<NN * SS * 2, 256, 0, stream>>>(x, Wa, ba, Wb, bb, part);
    k_softmax<<<NN * SS, 256, 0, stream>>>(p0, p1, A_base, PA, att);
    k_out<<<NN * (TT / 8), 256, 0, stream>>>(x, att, Wd, cmul, cadd, out);
}